// Round 9
// baseline (83.328 us; speedup 1.0000x reference)
//
#include <hip/hip_runtime.h>

// PatchQuantumGenerator, round 9: register build with ONE LDS round-trip
// per layer. Per layer the three cross-group steps (CNOT gather, q=1 mix,
// q=0 mix) collapse into a single 4-term gather-GEMM:
//   new[c] = sum_{v in {0,8,16,24}} K[b4(d)][b3(d)][v] * old[(d&7)|v],
// d = sigma_{l-1}(c) (identity for l=0), K = complex coeff products of the
// layer's q0/q1 gates. sigma_3 folds into the register init. Drains 25->9.
// GEMM phase / sincos staging / gate-matrix computation identical to r8
// (verified, absmax 0.0039).

#define NGEN 4
#define NLAY 4
#define NQ   5

typedef _Float16 half8 __attribute__((ext_vector_type(8)));
typedef float    f32x4 __attribute__((ext_vector_type(4)));

// In-wave LDS ordering (validated r6/r8): drain DS ops, forbid reordering.
#define WAVE_SYNC()                                                  \
    do {                                                             \
        __builtin_amdgcn_wave_barrier();                             \
        asm volatile("s_waitcnt lgkmcnt(0)" ::: "memory");           \
        __builtin_amdgcn_wave_barrier();                             \
    } while (0)

// CNOT chain of layer l as column-index map (ascending q; verified r5/r8).
__device__ __forceinline__ int sigma5(int v, int l) {
#pragma unroll
    for (int q = 0; q < NQ; ++q) {
        const int cb = 16 >> q;
        int tq = q + l + 1; if (tq >= NQ) tq -= NQ;
        const int tb = 16 >> tq;
        if (v & cb) v ^= tb;
    }
    return v;
}

__global__ __launch_bounds__(256) void pqg_fused(
    const float* __restrict__ x,      // [B,5]
    const float* __restrict__ wts,    // [4,4,5,3]
    float* __restrict__ out)          // [B,64]
{
    __shared__ float  gm[NGEN][NLAY * NQ * 8];   // gate matrices, per wave
    __shared__ float2 cs[NGEN][16 * 33];         // exchange scratch, per wave
    __shared__ float  scS[NGEN][640];            // sincos, per wave
    __shared__ float  scC[NGEN][640];

    const int t    = threadIdx.x;
    const int lane = t & 63;
    const int g    = t >> 6;              // wave index == generator
    const int b0   = blockIdx.x * 128;
    const int cg   = lane >> 4;           // col group (0..3)
    const int m    = lane & 15;           // row

    // ---- Gate matrices for this wave's g (lanes 0..19).
    // Rot = RZ(omega) RY(theta) RZ(phi); verified r1-r8.
    if (lane < NLAY * NQ) {
        const float* wp = wts + (g * (NLAY * NQ) + lane) * 3;
        const float phi = wp[0], theta = wp[1], omega = wp[2];
        const float a = 0.5f * (phi + omega);
        const float bb = 0.5f * (phi - omega);
        const float h = 0.5f * theta;
        const float sa = __sinf(a), ca = __cosf(a);
        const float sb = __sinf(bb), cb = __cosf(bb);
        const float st = __sinf(h), ct = __cosf(h);
        float* mm = &gm[g][lane * 8];
        mm[0] =  ca * ct;  mm[1] = -sa * ct;   // u00
        mm[2] = -cb * st;  mm[3] = -sb * st;   // u01
        mm[4] =  cb * st;  mm[5] = -sb * st;   // u10
        mm[6] =  ca * ct;  mm[7] =  sa * ct;   // u11
    }

    // ---- Sincos staging, wave-local (128 batches = 640 pairs).
#pragma unroll
    for (int e = 0; e < 10; ++e) {
        const int idx = e * 64 + lane;                  // 0..639
        const float tt = 0.5f * x[(size_t)b0 * 5 + idx];
        scS[g][idx] = __sinf(tt);
        scC[g][idx] = __cosf(tt);
    }
    WAVE_SYNC();   // gm + sincos visible within the wave

    // ---- M init: M = P with sigma_3 pre-applied: M[m][c] = (sigma3(c)==m).
    float mr[8], mi[8];
#pragma unroll
    for (int j = 0; j < 8; ++j) {
        mr[j] = (sigma5(cg * 8 + j, NLAY - 1) == m) ? 1.0f : 0.0f;
        mi[j] = 0.0f;
    }

    // ---- Build M = P*U, reverse circuit order (algebra from r8-verified
    // steps, composed): per layer: locals q4..q2 in regs, then ONE LDS
    // round-trip doing q1-mix + q0-mix + sigma_{l-1} gather.
#pragma unroll
    for (int l = NLAY - 1; l >= 0; --l) {
        // Rot gates q=4,3,2: lane-local register pairs (identical to r8).
#pragma unroll
        for (int q = NQ - 1; q >= 2; --q) {
            const float4 u0 = *(const float4*)&gm[g][(l * NQ + q) * 8];
            const float4 u1 = *(const float4*)&gm[g][(l * NQ + q) * 8 + 4];
            const float u00r = u0.x, u00i = u0.y, u01r = u0.z, u01i = u0.w;
            const float u10r = u1.x, u10i = u1.y, u11r = u1.z, u11i = u1.w;
            const int sb = 16 >> q;   // 1,2,4
#pragma unroll
            for (int ja = 0; ja < 8; ++ja) {
                if (!(ja & sb)) {
                    const int jb = ja | sb;
                    const float ar = mr[ja], ai = mi[ja];
                    const float br = mr[jb], bi = mi[jb];
                    mr[ja] = u00r * ar - u00i * ai + u10r * br - u10i * bi;
                    mi[ja] = u00r * ai + u00i * ar + u10r * bi + u10i * br;
                    mr[jb] = u01r * ar - u01i * ai + u11r * br - u11i * bi;
                    mi[jb] = u01r * ai + u01i * ar + u11r * bi + u11i * br;
                }
            }
        }

        // Combined q1-mix + q0-mix + sigma_{l-1} gather.
        // q=1 gate (bit 8): alpha1(b3)=b3?u01:u00, beta1(b3)=b3?u11:u10.
        // q=0 gate (bit 16): alpha0(b4)=b4?u01:u00, beta0(b4)=b4?u11:u10.
        // K[b4][b3][v]: v0=a0*a1, v8=a0*b1, v16=b0*a1, v24=b0*b1 (complex).
        {
            const float4 q1a = *(const float4*)&gm[g][(l * NQ + 1) * 8];
            const float4 q1b = *(const float4*)&gm[g][(l * NQ + 1) * 8 + 4];
            const float4 q0a = *(const float4*)&gm[g][(l * NQ + 0) * 8];
            const float4 q0b = *(const float4*)&gm[g][(l * NQ + 0) * 8 + 4];
            // a1[b3], b1[b3]
            const float a1r[2] = {q1a.x, q1a.z}, a1i[2] = {q1a.y, q1a.w};
            const float b1r[2] = {q1b.x, q1b.z}, b1i[2] = {q1b.y, q1b.w};
            // a0[b4], b0[b4]
            const float a0r[2] = {q0a.x, q0a.z}, a0i[2] = {q0a.y, q0a.w};
            const float b0r[2] = {q0b.x, q0b.z}, b0i[2] = {q0b.y, q0b.w};

            float Kr[2][2][4], Ki[2][2][4];
#pragma unroll
            for (int b4 = 0; b4 < 2; ++b4) {
#pragma unroll
                for (int b3 = 0; b3 < 2; ++b3) {
                    // v=0: a0*a1
                    Kr[b4][b3][0] = a0r[b4] * a1r[b3] - a0i[b4] * a1i[b3];
                    Ki[b4][b3][0] = a0r[b4] * a1i[b3] + a0i[b4] * a1r[b3];
                    // v=8: a0*b1
                    Kr[b4][b3][1] = a0r[b4] * b1r[b3] - a0i[b4] * b1i[b3];
                    Ki[b4][b3][1] = a0r[b4] * b1i[b3] + a0i[b4] * b1r[b3];
                    // v=16: b0*a1
                    Kr[b4][b3][2] = b0r[b4] * a1r[b3] - b0i[b4] * a1i[b3];
                    Ki[b4][b3][2] = b0r[b4] * a1i[b3] + b0i[b4] * a1r[b3];
                    // v=24: b0*b1
                    Kr[b4][b3][3] = b0r[b4] * b1r[b3] - b0i[b4] * b1i[b3];
                    Ki[b4][b3][3] = b0r[b4] * b1i[b3] + b0i[b4] * b1r[b3];
                }
            }

            // Write current regs to scratch.
#pragma unroll
            for (int j = 0; j < 8; ++j)
                cs[g][m * 33 + cg * 8 + j] = make_float2(mr[j], mi[j]);
            WAVE_SYNC();

            // Gather + 4-term complex accumulate. All indices compile-time.
#pragma unroll
            for (int j = 0; j < 8; ++j) {
                const int c = cg * 8 + j;
                const int d = (l > 0) ? sigma5(c, l - 1) : c;
                const int b4 = (d >> 4) & 1;
                const int b3 = (d >> 3) & 1;
                const int low = d & 7;
                const float2 s0  = cs[g][m * 33 + low];
                const float2 s8  = cs[g][m * 33 + low + 8];
                const float2 s16 = cs[g][m * 33 + low + 16];
                const float2 s24 = cs[g][m * 33 + low + 24];
                float nr, ni;
                nr  = Kr[b4][b3][0] * s0.x  - Ki[b4][b3][0] * s0.y;
                ni  = Kr[b4][b3][0] * s0.y  + Ki[b4][b3][0] * s0.x;
                nr += Kr[b4][b3][1] * s8.x  - Ki[b4][b3][1] * s8.y;
                ni += Kr[b4][b3][1] * s8.y  + Ki[b4][b3][1] * s8.x;
                nr += Kr[b4][b3][2] * s16.x - Ki[b4][b3][2] * s16.y;
                ni += Kr[b4][b3][2] * s16.y + Ki[b4][b3][2] * s16.x;
                nr += Kr[b4][b3][3] * s24.x - Ki[b4][b3][3] * s24.y;
                ni += Kr[b4][b3][3] * s24.y + Ki[b4][b3][3] * s24.x;
                mr[j] = nr; mi[j] = ni;
            }
            WAVE_SYNC();   // reads done before next layer's overwrite
        }
    }

    // ---- A-fragments: ownership already matches f16 A-frag layout.
    half8 Ar, Ai;
#pragma unroll
    for (int j = 0; j < 8; ++j) {
        Ar[j] = (_Float16)mr[j];
        Ai[j] = (_Float16)mi[j];
    }

    // ---- GEMM: identical to r8 (verified). 8 tiles x 16 batches.
    const int quad = cg;
    const int n    = m;

#pragma unroll
    for (int t8 = 0; t8 < 8; ++t8) {
        const int bl = t8 * 16 + n;
        const int b  = b0 + bl;
        const float* C = &scC[g][bl * 5];
        const float* S = &scS[g][bl * 5];

        // B-frag bit-map (verified r2): k=quad*8+j; quad&2->q0, quad&1->q1,
        // j&4->q2, j&2->q3, j&1->q4.
        const float f01 = ((quad & 2) ? S[0] : C[0]) * ((quad & 1) ? S[1] : C[1]);
        const float a0 = f01 * C[2], a1 = f01 * S[2];
        const float b00 = a0 * C[3], b01 = a0 * S[3];
        const float b10 = a1 * C[3], b11 = a1 * S[3];

        half8 Bf;
        Bf[0] = (_Float16)(b00 * C[4]);  Bf[1] = (_Float16)(b00 * S[4]);
        Bf[2] = (_Float16)(b01 * C[4]);  Bf[3] = (_Float16)(b01 * S[4]);
        Bf[4] = (_Float16)(b10 * C[4]);  Bf[5] = (_Float16)(b10 * S[4]);
        Bf[6] = (_Float16)(b11 * C[4]);  Bf[7] = (_Float16)(b11 * S[4]);

        f32x4 accR = {0.f, 0.f, 0.f, 0.f};
        f32x4 accI = {0.f, 0.f, 0.f, 0.f};
        accR = __builtin_amdgcn_mfma_f32_16x16x32_f16(Ar, Bf, accR, 0, 0, 0);
        accI = __builtin_amdgcn_mfma_f32_16x16x32_f16(Ai, Bf, accI, 0, 0, 0);

        // C/D: col = lane&15 (batch), row = quad*4 + reg (output k).
        const float p0 = accR[0] * accR[0] + accI[0] * accI[0];
        const float p1 = accR[1] * accR[1] + accI[1] * accI[1];
        const float p2 = accR[2] * accR[2] + accI[2] * accI[2];
        const float p3 = accR[3] * accR[3] + accI[3] * accI[3];

        float mx = fmaxf(fmaxf(p0, p1), fmaxf(p2, p3));
        mx = fmaxf(mx, __shfl_xor(mx, 16));
        mx = fmaxf(mx, __shfl_xor(mx, 32));
        const float inv = 1.0f / mx;

        const float4 o = make_float4(p0 * inv, p1 * inv, p2 * inv, p3 * inv);
        *(float4*)(out + (size_t)b * 64 + g * 16 + quad * 4) = o;
    }
}

extern "C" void kernel_launch(void* const* d_in, const int* in_sizes, int n_in,
                              void* d_out, int out_size, void* d_ws, size_t ws_size,
                              hipStream_t stream) {
    const float* x = (const float*)d_in[0];   // [B, 5]
    const float* w = (const float*)d_in[1];   // [4, 4, 5, 3]
    float* out = (float*)d_out;               // [B, 64]
    const int B = in_sizes[0] / NQ;           // 65536

    // 512 blocks of (128 batches x 4 independent waves, one per g).
    pqg_fused<<<B / 128, 256, 0, stream>>>(x, w, out);
}

// Round 10
// 71.668 us; speedup vs baseline: 1.1627x; 1.1627x over previous
//
#include <hip/hip_runtime.h>

// PatchQuantumGenerator, round 10: r8's verified build (register-resident M,
// CNOT gather + LDS cross-gates + lane-local gates), with MINIMAL CODE SIZE:
// layer loop, GEMM tile loop, and sincos staging are rolled. Theory: the
// 268MB ws-poison before each replay flushes L2/LLC, so kernel text is
// cold-fetched every iteration -- cost scales with text size (r2->r3 -14us).
// No runtime-indexed register arrays (r9's spill bug avoided).

#define NGEN 4
#define NLAY 4
#define NQ   5

typedef _Float16 half8 __attribute__((ext_vector_type(8)));
typedef float    f32x4 __attribute__((ext_vector_type(4)));

// In-wave LDS ordering (validated r6/r8): drain DS ops, forbid reordering.
#define WAVE_SYNC()                                                  \
    do {                                                             \
        __builtin_amdgcn_wave_barrier();                             \
        asm volatile("s_waitcnt lgkmcnt(0)" ::: "memory");           \
        __builtin_amdgcn_wave_barrier();                             \
    } while (0)

// Lane-local Rot right-mult (gate qubit bit SB within a lane's 8 columns).
// col_i <- u00*ci + u10*cj ; col_j <- u01*ci + u11*cj   (verified r8)
template <int SB>
__device__ __forceinline__ void local_gate(const float* gmg, int idx,
                                           float (&mr)[8], float (&mi)[8]) {
    const float4 u0 = *(const float4*)&gmg[idx * 8];
    const float4 u1 = *(const float4*)&gmg[idx * 8 + 4];
#pragma unroll
    for (int ja = 0; ja < 8; ++ja) {
        if (!(ja & SB)) {
            const int jb = ja | SB;
            const float ar = mr[ja], ai = mi[ja];
            const float br = mr[jb], bi = mi[jb];
            mr[ja] = u0.x * ar - u0.y * ai + u1.x * br - u1.y * bi;
            mi[ja] = u0.x * ai + u0.y * ar + u1.x * bi + u1.y * br;
            mr[jb] = u0.z * ar - u0.w * ai + u1.z * br - u1.w * bi;
            mi[jb] = u0.z * ai + u0.w * ar + u1.z * bi + u1.w * br;
        }
    }
}

// Cross-group Rot (gate bit SB = 8 or 16) via LDS scratch, full two-term
// formula reading both pair columns (verified r8).
template <int SB>
__device__ __forceinline__ void cross_gate(const float* gmg, int idx,
                                           float2* csg, int cg, int m,
                                           float (&mr)[8], float (&mi)[8]) {
    const float4 u0 = *(const float4*)&gmg[idx * 8];
    const float4 u1 = *(const float4*)&gmg[idx * 8 + 4];
#pragma unroll
    for (int j = 0; j < 8; ++j)
        csg[m * 33 + cg * 8 + j] = make_float2(mr[j], mi[j]);
    WAVE_SYNC();
    const int ibase = (cg * 8) & ~SB;
    const int jbase = (cg * 8) |  SB;
    const bool hi = ((cg * 8) & SB) != 0;
    const float k0r = hi ? u0.z : u0.x, k0i = hi ? u0.w : u0.y;
    const float k1r = hi ? u1.z : u1.x, k1i = hi ? u1.w : u1.y;
#pragma unroll
    for (int j = 0; j < 8; ++j) {
        const float2 A2 = csg[m * 33 + ibase + j];
        const float2 B2 = csg[m * 33 + jbase + j];
        mr[j] = k0r * A2.x - k0i * A2.y + k1r * B2.x - k1i * B2.y;
        mi[j] = k0r * A2.y + k0i * A2.x + k1r * B2.y + k1i * B2.x;
    }
    WAVE_SYNC();
}

__global__ __launch_bounds__(256) void pqg_fused(
    const float* __restrict__ x,      // [B,5]
    const float* __restrict__ wts,    // [4,4,5,3]
    float* __restrict__ out)          // [B,64]
{
    __shared__ float  gm[NGEN][NLAY * NQ * 8];
    __shared__ float2 cs[NGEN][16 * 33];
    __shared__ float  scS[NGEN][640];
    __shared__ float  scC[NGEN][640];

    const int t    = threadIdx.x;
    const int lane = t & 63;
    const int g    = t >> 6;              // wave index == generator
    const int b0   = blockIdx.x * 128;
    const int cg   = lane >> 4;           // col group (0..3)
    const int m    = lane & 15;           // row

    // ---- Gate matrices (Rot = RZ(omega) RY(theta) RZ(phi); verified r1-r8).
    if (lane < NLAY * NQ) {
        const float* wp = wts + (g * (NLAY * NQ) + lane) * 3;
        const float phi = wp[0], theta = wp[1], omega = wp[2];
        const float a = 0.5f * (phi + omega);
        const float bb = 0.5f * (phi - omega);
        const float h = 0.5f * theta;
        const float sa = __sinf(a), ca = __cosf(a);
        const float sb = __sinf(bb), cb = __cosf(bb);
        const float st = __sinf(h), ct = __cosf(h);
        float* mm = &gm[g][lane * 8];
        mm[0] =  ca * ct;  mm[1] = -sa * ct;   // u00
        mm[2] = -cb * st;  mm[3] = -sb * st;   // u01
        mm[4] =  cb * st;  mm[5] = -sb * st;   // u10
        mm[6] =  ca * ct;  mm[7] =  sa * ct;   // u11
    }

    // ---- Sincos staging, wave-local (rolled).
#pragma clang loop unroll(disable)
    for (int e = 0; e < 10; ++e) {
        const int idx = e * 64 + lane;                  // 0..639
        const float tt = 0.5f * x[(size_t)b0 * 5 + idx];
        scS[g][idx] = __sinf(tt);
        scC[g][idx] = __cosf(tt);
    }
    WAVE_SYNC();

    // ---- M init: M = P. Lane holds row m, cols cg*8+j.
    float mr[8], mi[8];
#pragma unroll
    for (int j = 0; j < 8; ++j) {
        mr[j] = (cg * 8 + j == m) ? 1.0f : 0.0f;
        mi[j] = 0.0f;
    }

    // ---- Build M = P*U, reverse circuit order (r8 algebra; l-loop ROLLED).
#pragma clang loop unroll(disable)
    for (int l = NLAY - 1; l >= 0; --l) {
        // CNOT group: new[.,c] = old[.,sigma_l(c)] (ascending-q cond-XOR).
#pragma unroll
        for (int j = 0; j < 8; ++j)
            cs[g][m * 33 + cg * 8 + j] = make_float2(mr[j], mi[j]);
        WAVE_SYNC();
        {
            float2 tmp[8];
#pragma unroll
            for (int j = 0; j < 8; ++j) {
                int v = cg * 8 + j;
#pragma unroll
                for (int q = 0; q < NQ; ++q) {
                    const int cb = 16 >> q;
                    int tq = q + l + 1; if (tq >= NQ) tq -= NQ;
                    const int tb = 16 >> tq;
                    if (v & cb) v ^= tb;
                }
                tmp[j] = cs[g][m * 33 + v];
            }
            WAVE_SYNC();
#pragma unroll
            for (int j = 0; j < 8; ++j) { mr[j] = tmp[j].x; mi[j] = tmp[j].y; }
        }

        // Rot gates reverse order: q=4,3,2 lane-local; q=1,0 cross-group.
        local_gate<1>(gm[g], l * NQ + 4, mr, mi);
        local_gate<2>(gm[g], l * NQ + 3, mr, mi);
        local_gate<4>(gm[g], l * NQ + 2, mr, mi);
        cross_gate<8> (gm[g], l * NQ + 1, cs[g], cg, m, mr, mi);
        cross_gate<16>(gm[g], l * NQ + 0, cs[g], cg, m, mr, mi);
    }

    // ---- A-fragments: ownership already matches f16 A-frag layout.
    half8 Ar, Ai;
#pragma unroll
    for (int j = 0; j < 8; ++j) {
        Ar[j] = (_Float16)mr[j];
        Ai[j] = (_Float16)mi[j];
    }

    // ---- GEMM (r8, verified): 8 tiles x 16 batches; tile loop ROLLED.
    const int quad = cg;
    const int n    = m;

#pragma clang loop unroll(disable)
    for (int t8 = 0; t8 < 8; ++t8) {
        const int bl = t8 * 16 + n;
        const int b  = b0 + bl;
        const float* C = &scC[g][bl * 5];
        const float* S = &scS[g][bl * 5];

        // B-frag bit-map (verified r2): k=quad*8+j; quad&2->q0, quad&1->q1,
        // j&4->q2, j&2->q3, j&1->q4.
        const float f01 = ((quad & 2) ? S[0] : C[0]) * ((quad & 1) ? S[1] : C[1]);
        const float a0 = f01 * C[2], a1 = f01 * S[2];
        const float b00 = a0 * C[3], b01 = a0 * S[3];
        const float b10 = a1 * C[3], b11 = a1 * S[3];

        half8 Bf;
        Bf[0] = (_Float16)(b00 * C[4]);  Bf[1] = (_Float16)(b00 * S[4]);
        Bf[2] = (_Float16)(b01 * C[4]);  Bf[3] = (_Float16)(b01 * S[4]);
        Bf[4] = (_Float16)(b10 * C[4]);  Bf[5] = (_Float16)(b10 * S[4]);
        Bf[6] = (_Float16)(b11 * C[4]);  Bf[7] = (_Float16)(b11 * S[4]);

        f32x4 accR = {0.f, 0.f, 0.f, 0.f};
        f32x4 accI = {0.f, 0.f, 0.f, 0.f};
        accR = __builtin_amdgcn_mfma_f32_16x16x32_f16(Ar, Bf, accR, 0, 0, 0);
        accI = __builtin_amdgcn_mfma_f32_16x16x32_f16(Ai, Bf, accI, 0, 0, 0);

        // C/D: col = lane&15 (batch), row = quad*4 + reg (output k).
        const float p0 = accR[0] * accR[0] + accI[0] * accI[0];
        const float p1 = accR[1] * accR[1] + accI[1] * accI[1];
        const float p2 = accR[2] * accR[2] + accI[2] * accI[2];
        const float p3 = accR[3] * accR[3] + accI[3] * accI[3];

        float mx = fmaxf(fmaxf(p0, p1), fmaxf(p2, p3));
        mx = fmaxf(mx, __shfl_xor(mx, 16));
        mx = fmaxf(mx, __shfl_xor(mx, 32));
        const float inv = 1.0f / mx;

        const float4 o = make_float4(p0 * inv, p1 * inv, p2 * inv, p3 * inv);
        *(float4*)(out + (size_t)b * 64 + g * 16 + quad * 4) = o;
    }
}

extern "C" void kernel_launch(void* const* d_in, const int* in_sizes, int n_in,
                              void* d_out, int out_size, void* d_ws, size_t ws_size,
                              hipStream_t stream) {
    const float* x = (const float*)d_in[0];   // [B, 5]
    const float* w = (const float*)d_in[1];   // [4, 4, 5, 3]
    float* out = (float*)d_out;               // [B, 64]
    const int B = in_sizes[0] / NQ;           // 65536

    // 512 blocks of (128 batches x 4 independent waves, one per g).
    pqg_fused<<<B / 128, 256, 0, stream>>>(x, w, out);
}